// Round 8
// baseline (170.718 us; speedup 1.0000x reference)
//
#include <hip/hip_runtime.h>
#include <hip/hip_bf16.h>

// 8-layer MLP, B=131072, fused. R7 vs R5:
//  - R5 post-mortem: per-layer wall (18K cyc/CU) == MFMA + VALU + LDS demand
//    SUMMED -> zero pipe overlap. Causes: depth-1 weight prefetch (per-kk
//    vmcnt drain vs ~200cyc L2 latency) + 2 barriers/layer (epilogue VALU
//    phase barrier-serialized against K-loop MFMA phase).
//  - Fix 1: depth-2 prefetch ring wb[3][2]; continuous g=16L+kk index, fully
//    unrolled 6x16 -> all-static slot indices + immediate addressing.
//  - Fix 2: ping-pong Hs[2]: read Hs[L&1], write Hs[(L+1)&1], ONE barrier per
//    layer; finishing waves' epilogue overlaps other waves' MFMA.
//  - LDS 144KB -> one 512-thread block per CU, launch_bounds(512,1) (256 VGPR
//    headroom for the ring). W7 frags hoisted to kernel start.

#define HID 256
#define BM 128
#define NBLK 1024      // 131072 / 128
#define HPITCH 264

typedef __attribute__((ext_vector_type(8))) short bf16x8;
typedef __attribute__((ext_vector_type(8))) unsigned short u16x8;
typedef __attribute__((ext_vector_type(4))) unsigned short u16x4;
typedef __attribute__((ext_vector_type(4))) float f32x4;
typedef __attribute__((ext_vector_type(16))) float f32x16;

__device__ __forceinline__ unsigned cvt_pk_bf16(float lo, float hi) {
    unsigned r;
    asm("v_cvt_pk_bf16_f32 %0, %1, %2" : "=v"(r) : "v"(lo), "v"(hi));
    return r;
}

struct WPtrs { const float* w[6]; const float* w7; };

// Pack W1..W6 as 32x32x16 A-frags (unchanged from R5, verified):
//   frag (L,fw,kk,ft): lane l, elem j = W_L[64fw+32ft+(l&31)][16kk+8(l>>5)+j]
//   at Wp[(((L*4+fw)*16+kk)*2+ft)*64*8 + l*8]
// W7 as 16x16x32 A-frags (rows 3..15 zero) at Wp+393216.
__global__ void pack_w_kernel(WPtrs wp, unsigned short* __restrict__ Wp) {
    int tid = blockIdx.x * 256 + threadIdx.x;
    if (tid < 49152) {
        int l  = tid & 63;
        int ft = (tid >> 6) & 1;
        int kk = (tid >> 7) & 15;
        int fw = (tid >> 11) & 3;
        int L  = tid >> 13;
        int n  = 64 * fw + 32 * ft + (l & 31);
        int k0 = 16 * kk + 8 * (l >> 5);
        const float* src = wp.w[L] + n * HID + k0;
        u16x8 v;
#pragma unroll
        for (int j = 0; j < 8; ++j) {
            union { float f; unsigned u; } c; c.f = src[j];
            unsigned r = c.u + 0x7fffu + ((c.u >> 16) & 1u);  // RNE
            v[j] = (unsigned short)(r >> 16);
        }
        *(u16x8*)(Wp + (size_t)tid * 8) = v;
    } else if (tid < 49664) {
        int t  = tid - 49152;
        int l  = t & 63;
        int kk = t >> 6;                 // 0..7
        int n  = l & 15;
        int k0 = 32 * kk + 8 * (l >> 4);
        u16x8 v;
#pragma unroll
        for (int j = 0; j < 8; ++j) {
            unsigned short s = 0;
            if (n < 3) {
                union { float f; unsigned u; } c; c.f = wp.w7[n * HID + k0 + j];
                s = (unsigned short)((c.u + 0x7fffu + ((c.u >> 16) & 1u)) >> 16);
            }
            v[j] = s;
        }
        *(u16x8*)(Wp + 393216 + (size_t)t * 8) = v;
    }
}

__launch_bounds__(512, 1)
__global__ void mlp_fused_kernel(const float* __restrict__ x,
                                 const float* __restrict__ W0,
                                 const unsigned short* __restrict__ Wp,
                                 float* __restrict__ out) {
    __shared__ __align__(16) unsigned short Hs[2][BM][HPITCH]; // 135,168 B
    __shared__ __align__(16) float Ps[4][BM][4];               // 8,192 B
    __shared__ float xsf[2 * BM];                              // 1,024 B

    const int tid = threadIdx.x;
    const int l   = tid & 63;
    const int w   = tid >> 6;        // 0..7
    const int fw  = w & 3;           // feature slice [64fw, 64fw+64)
    const int rb  = (w >> 2) * 64;   // row half base
    const long r0 = (long)blockIdx.x * BM;

    const unsigned short* wbl = Wp + (size_t)fw * 16384 + (size_t)l * 8;

    // depth-2 prefetch ring: slot g%3 holds weights for step g = 16L+kk
    bf16x8 wb[3][2];
    wb[0][0] = *(const bf16x8*)(wbl);
    wb[0][1] = *(const bf16x8*)(wbl + 512);
    wb[1][0] = *(const bf16x8*)(wbl + 1024);
    wb[1][1] = *(const bf16x8*)(wbl + 1536);

    // hoist layer-7 weight frags (8 VGPR, live through kernel)
    const unsigned short* w7b = Wp + 393216 + (size_t)l * 8;
    bf16x8 w7f0 = *(const bf16x8*)(w7b + (2 * fw) * 512);
    bf16x8 w7f1 = *(const bf16x8*)(w7b + (2 * fw + 1) * 512);

    // ---- stage x ----
    if (tid < 2 * BM) xsf[tid] = x[r0 * 2 + tid];
    const int fp = (tid & 127) * 2;          // feature pair
    const int q  = tid >> 7;                 // row quarter (0..3)
    f32x4 w0v = *(const f32x4*)(W0 + 2 * fp);
    __syncthreads();

    // ---- layer 0: relu(x @ W0.T) -> bf16 Hs[0] ----
#pragma unroll
    for (int i = 0; i < 32; ++i) {
        int m = 32 * q + i;
        float x0 = xsf[2 * m], x1 = xsf[2 * m + 1];
        float ha = fmaf(x0, w0v[0], x1 * w0v[1]);
        float hb = fmaf(x0, w0v[2], x1 * w0v[3]);
        *(unsigned*)(&Hs[0][m][fp]) = cvt_pk_bf16(fmaxf(0.f, ha), fmaxf(0.f, hb));
    }
    __syncthreads();

    // ---- layers 1..6: 32x32x16 MFMA; read Hs[L&1], write Hs[(L+1)&1] ----
    const int c  = l & 31;
    const int hi = l >> 5;
#pragma unroll
    for (int L = 0; L < 6; ++L) {
        const int rp = L & 1, wp2 = rp ^ 1;
        f32x16 acc[2][2];      // [ft][mt]
#pragma unroll
        for (int ft = 0; ft < 2; ++ft)
#pragma unroll
            for (int mt = 0; mt < 2; ++mt)
#pragma unroll
                for (int j = 0; j < 16; ++j) acc[ft][mt][j] = 0.f;

#pragma unroll
        for (int kk = 0; kk < 16; ++kk) {
            const int g   = 16 * L + kk;
            const int cur = g % 3;
            const int pre = (g + 2) % 3;
            if (g + 2 < 96) {     // prefetch step g+2 (crosses layer boundary)
                const int gl = (g + 2) >> 4, gk = (g + 2) & 15;
                wb[pre][0] = *(const bf16x8*)(wbl + gl * 65536 + gk * 1024);
                wb[pre][1] = *(const bf16x8*)(wbl + gl * 65536 + gk * 1024 + 512);
            }
            bf16x8 a0 = *(const bf16x8*)(&Hs[rp][rb + c][16 * kk + 8 * hi]);
            bf16x8 a1 = *(const bf16x8*)(&Hs[rp][rb + 32 + c][16 * kk + 8 * hi]);
            acc[0][0] = __builtin_amdgcn_mfma_f32_32x32x16_bf16(wb[cur][0], a0, acc[0][0], 0, 0, 0);
            acc[0][1] = __builtin_amdgcn_mfma_f32_32x32x16_bf16(wb[cur][0], a1, acc[0][1], 0, 0, 0);
            acc[1][0] = __builtin_amdgcn_mfma_f32_32x32x16_bf16(wb[cur][1], a0, acc[1][0], 0, 0, 0);
            acc[1][1] = __builtin_amdgcn_mfma_f32_32x32x16_bf16(wb[cur][1], a1, acc[1][1], 0, 0, 0);
        }
        // epilogue -> other buffer; no pre-barrier needed (reads were from rp)
        // D: lane holds batch row rb+32mt+c, features 64fw+32ft+8g2+4hi+{0..3}
#pragma unroll
        for (int ft = 0; ft < 2; ++ft)
#pragma unroll
            for (int mt = 0; mt < 2; ++mt) {
                f32x16 v = acc[ft][mt];
#pragma unroll
                for (int g2 = 0; g2 < 4; ++g2) {
                    union { unsigned u[2]; u16x4 s; } pk;
                    pk.u[0] = cvt_pk_bf16(fmaxf(0.f, v[4 * g2]),     fmaxf(0.f, v[4 * g2 + 1]));
                    pk.u[1] = cvt_pk_bf16(fmaxf(0.f, v[4 * g2 + 2]), fmaxf(0.f, v[4 * g2 + 3]));
                    *(u16x4*)(&Hs[wp2][rb + 32 * mt + c][64 * fw + 32 * ft + 8 * g2 + 4 * hi]) = pk.s;
                }
            }
        __syncthreads();   // single barrier per layer
    }

    // ---- layer 7 (16x16x32): final acts in Hs[0]; wave w -> rows [rb,rb+64),
    //      K slices {2fw, 2fw+1} ----
    const int lr = l & 15, lg = l >> 4;
    f32x4 acc7[4];
#pragma unroll
    for (int mt = 0; mt < 4; ++mt) acc7[mt] = (f32x4){0.f, 0.f, 0.f, 0.f};
#pragma unroll
    for (int mt = 0; mt < 4; ++mt) {
        bf16x8 a = *(const bf16x8*)(&Hs[0][rb + 16 * mt + lr][32 * (2 * fw) + 8 * lg]);
        acc7[mt] = __builtin_amdgcn_mfma_f32_16x16x32_bf16(w7f0, a, acc7[mt], 0, 0, 0);
        bf16x8 b = *(const bf16x8*)(&Hs[0][rb + 16 * mt + lr][32 * (2 * fw + 1) + 8 * lg]);
        acc7[mt] = __builtin_amdgcn_mfma_f32_16x16x32_bf16(w7f1, b, acc7[mt], 0, 0, 0);
    }
    if (lg == 0) {
#pragma unroll
        for (int mt = 0; mt < 4; ++mt)
            *(f32x4*)(&Ps[fw][rb + 16 * mt + lr][0]) = acc7[mt];
    }
    __syncthreads();
    // ---- reduce 4 K-partials + sigmoid ----
    if (tid < 3 * BM) {
        int row = tid / 3, o = tid - 3 * row;
        float s = Ps[0][row][o] + Ps[1][row][o] + Ps[2][row][o] + Ps[3][row][o];
        out[r0 * 3 + tid] = 1.f / (1.f + __expf(-s));
    }
}

extern "C" void kernel_launch(void* const* d_in, const int* in_sizes, int n_in,
                              void* d_out, int out_size, void* d_ws, size_t ws_size,
                              hipStream_t stream) {
    const float* x  = (const float*)d_in[0];
    const float* W0 = (const float*)d_in[1];
    WPtrs wp;
    for (int i = 0; i < 6; ++i) wp.w[i] = (const float*)d_in[2 + i];
    wp.w7 = (const float*)d_in[8];
    float* out = (float*)d_out;
    unsigned short* Wp = (unsigned short*)d_ws;   // 794,624 B used

    pack_w_kernel<<<194, 256, 0, stream>>>(wp, Wp);
    mlp_fused_kernel<<<NBLK, 512, 0, stream>>>(x, W0, Wp, out);
}